// Round 13
// baseline (46.010 us; speedup 1.0000x reference)
//
#include <hip/hip_runtime.h>
#include <hip/hip_bf16.h>
#include <math.h>

// Problem constants
#define Bn 8
#define Cn 64
#define Hn 128
#define Wn 128
#define Rn 4

typedef __bf16 v8bf __attribute__((ext_vector_type(8)));
typedef float  v16f __attribute__((ext_vector_type(16)));

__device__ __forceinline__ float leaky(float x) { return x >= 0.f ? x : 0.1f * x; }

__device__ __forceinline__ unsigned bf16pair(float a, float b) {
    __hip_bfloat16 ha = __float2bfloat16(a);
    __hip_bfloat16 hb = __float2bfloat16(b);
    return (unsigned)*reinterpret_cast<unsigned short*>(&ha) |
           ((unsigned)*reinterpret_cast<unsigned short*>(&hb) << 16);
}

// ---------------------------------------------------------------------------
// Kernel A: per-batch dynamic depthwise kernels + channel attn; block Bn
// converts w_conv -> bf16 [o][c].
//   kern_g[b][c][r][9]  (b*2304 + c*36 + r*9 + kk)
//   att_g [b][r][c]
// ---------------------------------------------------------------------------
__global__ __launch_bounds__(256) void precomp_kernel(
    const float* __restrict__ deg, const float* __restrict__ w_k1,
    const float* __restrict__ w_k2, const float* __restrict__ w_ca1,
    const float* __restrict__ w_ca2, const float* __restrict__ w_conv,
    float* __restrict__ kern_g, float* __restrict__ att_g,
    unsigned short* __restrict__ wbf)
{
    const int tid = threadIdx.x;
    if (blockIdx.x == Bn) {                       // w_conv -> bf16
        for (int f = tid; f < Cn * Cn; f += 256) {
            __hip_bfloat16 hx = __float2bfloat16(w_conv[f]);
            wbf[f] = *reinterpret_cast<unsigned short*>(&hx);
        }
        return;
    }
    const int b = blockIdx.x;
    __shared__ float y_s[64], a_s[64];
    if (tid < 64) {
        float sy = 0.f, sa = 0.f;
#pragma unroll 8
        for (int j = 0; j < 64; ++j) {
            float d = deg[b * 64 + j];
            sy += d * w_k1[tid * 64 + j];
            sa += d * w_ca1[tid * 64 + j];
        }
        y_s[tid] = leaky(sy);
        a_s[tid] = leaky(sa);
    }
    __syncthreads();
    for (int f = tid; f < Cn * Rn * 9; f += 256) {
        int c = f / 36;
        int j = f - c * 36;
        int r = j / 9;
        int kk = j - r * 9;
        int o = c * 9 + kk;
        const float* wp = &w_k2[(r * 576 + o) * 16];
        const float* yp = &y_s[r * 16];
        float s = 0.f;
#pragma unroll
        for (int i = 0; i < 16; ++i) s += yp[i] * wp[i];
        kern_g[b * 2304 + f] = s;
    }
    {
        int r = tid >> 6, o = tid & 63;
        const float* wp = &w_ca2[(r * 64 + o) * 16];
        const float* ap = &a_s[r * 16];
        float s = 0.f;
#pragma unroll
        for (int i = 0; i < 16; ++i) s += ap[i] * wp[i];
        att_g[b * 256 + tid] = 1.f / (1.f + expf(-s));
    }
}

// ---------------------------------------------------------------------------
// Main kernel: one block per (b,h) row, 512 threads = 8 waves, 2 barriers.
// R12 + (a) 2-deep software pipeline (pairs p+1, p+2 in flight),
// (b) pairs 0-1 prefetched BEFORE the barrier (independent of ridx),
// (c) subtiled t_lds[cq][w][8] with 2 conflict-free ds_write_b128/thread
//     (uint4 accumulated across 4 pairs) -- R8-verified layout.
// ---------------------------------------------------------------------------
__global__ __launch_bounds__(512) void da_main(
    const float* __restrict__ x0, const float* __restrict__ q_map,
    const unsigned short* __restrict__ wbf, const float* __restrict__ b_conv,
    const float* __restrict__ w_g1, const float* __restrict__ b_g1,
    const float* __restrict__ w_g2, const float* __restrict__ b_g2,
    const float* __restrict__ kern_g, const float* __restrict__ att_g,
    float* __restrict__ out)
{
    __shared__ __align__(16) float kern_lds[Cn * 48];           // 12 KB
    __shared__ __align__(16) unsigned short wc_lds[8][Cn][8];   // 8 KB
    __shared__ __align__(16) unsigned short t_lds[8][Wn][8];    // 16 KB (subtiled)
    __shared__ float att_lds[Rn * 68];                          // 1.1 KB
    __shared__ float bias_lds[Cn];                              // 0.25 KB
    __shared__ unsigned ridx[Wn];                               // 0.5 KB  r1 | r2<<16

    const int tid = threadIdx.x;
    const int ob = blockIdx.x;
    // XCD-aware swizzle: XCD i gets batch i (4 MB image == one L2).
    const int sb = ((ob & 7) << 7) | (ob >> 3);
    const int b = sb >> 7;
    const int h = sb & 127;

    const int lane = tid & 63;
    const int w = tid & 127;
    const int q = tid >> 7;               // channel quarter: [16q, 16q+16)

    // ---- phase 0: staging ----
    for (int f = tid; f < Cn * Rn * 9; f += 512) {
        int c = f / 36;
        int j = f - c * 36;
        int r = j / 9;
        int kk = j - r * 9;
        kern_lds[c * 48 + r * 12 + kk] = kern_g[b * 2304 + f];
    }
    {   // wc subtiles: one conflict-free b128 write per thread
        int cq = tid & 7, o = tid >> 3;
        *(v8bf*)&wc_lds[cq][o][0] = *(const v8bf*)&wbf[o * 64 + cq * 8];
    }
    if (tid < 256) att_lds[(tid >> 6) * 68 + (tid & 63)] = att_g[b * 256 + tid];
    if (tid < 64) bias_lds[tid] = b_conv[tid];

    // routing: once per column, published packed (r1 | r2<<16)
    if (tid < 128) {
        const int wc = tid;
        float qv[9];
#pragma unroll
        for (int dh = 0; dh < 3; ++dh) {
            int row = h - 1 + dh;
#pragma unroll
            for (int dw = 0; dw < 3; ++dw) {
                int col = wc - 1 + dw;
                qv[dh * 3 + dw] = (row >= 0 && row < Hn && col >= 0 && col < Wn)
                                      ? q_map[(b * Hn + row) * Wn + col] : 0.f;
            }
        }
        float best1 = -1e30f, best2 = -1e30f;
        int r1 = 0, r2 = 0;
#pragma unroll
        for (int r = 0; r < Rn; ++r) {
            float s1 = b_g1[r], s2 = b_g2[r];
#pragma unroll
            for (int k = 0; k < 9; ++k) {
                s1 += qv[k] * w_g1[r * 9 + k];
                s2 += qv[k] * w_g2[r * 9 + k];
            }
            if (s1 > best1) { best1 = s1; r1 = r; }   // strict > == first argmax
            if (s2 > best2) { best2 = s2; r2 = r; }
        }
        ridx[wc] = (unsigned)r1 | ((unsigned)r2 << 16);
    }

    // ---- pre-barrier prefetch of pairs 0 and 1 (independent of ridx) ----
    const bool okm = (h > 0);
    const bool okp = (h < Hn - 1);
    const float* xbase = x0 + (size_t)(b * Cn) * Hn * Wn + h * Wn + w;
    const int eoff = (lane == 0) ? ((w == 0) ? 0 : -1)
                   : (lane == 63) ? ((w == 127) ? 0 : 1) : 0;
    const bool eok = !((lane == 0 && w == 0) || (lane == 63 && w == 127));

    float pvm[2][2], pv0[2][2], pvp[2][2], pem[2][2], pe0[2][2], pep[2][2];

#define LOADP(P, B)                                                       \
    do {                                                                  \
        _Pragma("unroll")                                                 \
        for (int u = 0; u < 2; ++u) {                                     \
            const float* xc = xbase + (16 * q + 2 * (P) + u) * (Hn * Wn); \
            pvm[B][u] = okm ? xc[-Wn] : 0.f;                              \
            pv0[B][u] = xc[0];                                            \
            pvp[B][u] = okp ? xc[Wn] : 0.f;                               \
            const float* xe = xc + eoff;                                  \
            pem[B][u] = okm ? xe[-Wn] : 0.f;                              \
            pe0[B][u] = xe[0];                                            \
            pep[B][u] = okp ? xe[Wn] : 0.f;                               \
        }                                                                 \
    } while (0)

    LOADP(0, 0);
    LOADP(1, 1);

    __syncthreads();

    // ---- phase 1: depthwise conv, 16 channels/thread, 2-deep pipeline ----
    const int r1 = (int)(ridx[w] & 0xffffu);
    uint4 pk;

#pragma unroll
    for (int p = 0; p < 8; ++p) {
        const int B = p & 1;                      // compile-time after unroll
        float avm[2] = {pvm[B][0], pvm[B][1]};
        float av0[2] = {pv0[B][0], pv0[B][1]};
        float avp[2] = {pvp[B][0], pvp[B][1]};
        float aem[2] = {pem[B][0], pem[B][1]};
        float ae0[2] = {pe0[B][0], pe0[B][1]};
        float aep[2] = {pep[B][0], pep[B][1]};
        if (p < 6) LOADP(p + 2, B);               // refill freed buffer

        float tt[2];
#pragma unroll
        for (int u = 0; u < 2; ++u) {
            const int c = 16 * q + 2 * p + u;
            float vm = avm[u], v0 = av0[u], vp = avp[u];
            float lm = __shfl_up(vm, 1), l0 = __shfl_up(v0, 1), lp = __shfl_up(vp, 1);
            float rm = __shfl_down(vm, 1), r0 = __shfl_down(v0, 1), rp = __shfl_down(vp, 1);
            float em = eok ? aem[u] : 0.f;
            float e0 = eok ? ae0[u] : 0.f;
            float ep = eok ? aep[u] : 0.f;
            if (lane == 0)  { lm = em; l0 = e0; lp = ep; }
            if (lane == 63) { rm = em; r0 = e0; rp = ep; }
            const float* kp = &kern_lds[c * 48 + r1 * 12];   // 4-addr multicast
            float4 k03 = *(const float4*)kp;
            float4 k47 = *(const float4*)(kp + 4);
            float k8 = kp[8];
            float t = lm * k03.x + vm * k03.y + rm * k03.z
                    + l0 * k03.w + v0 * k47.x + r0 * k47.y
                    + lp * k47.z + vp * k47.w + rp * k8;
            tt[u] = leaky(t);
        }
        unsigned qq = bf16pair(tt[0], tt[1]);
        if (p == 0) pk.x = qq;
        else if (p == 1) pk.y = qq;
        else if (p == 2) pk.z = qq;
        else if (p == 3) { pk.w = qq; *(uint4*)&t_lds[2 * q][w][0] = pk; }
        else if (p == 4) pk.x = qq;
        else if (p == 5) pk.y = qq;
        else if (p == 6) pk.z = qq;
        else             { pk.w = qq; *(uint4*)&t_lds[2 * q + 1][w][0] = pk; }
    }
#undef LOADP
    __syncthreads();

    // ---- phase 2: MFMA channel mix + fused epilogue (verified path) ----
    const int v = tid >> 6;               // wave 0..7
    const int wt = v & 3;                 // w-tile (32 cols)
    const int oh = v >> 2;                // o-half (32 rows)
    const int col = lane & 31;
    const int kh = lane >> 5;
    const int wn = wt * 32 + col;         // this lane's output column

    v8bf Bf[4];
#pragma unroll
    for (int ks = 0; ks < 4; ++ks)
        Bf[ks] = *(const v8bf*)&t_lds[2 * ks + kh][wn][0];

    v16f acc;
#pragma unroll
    for (int i = 0; i < 16; ++i) acc[i] = 0.f;

#pragma unroll
    for (int ks = 0; ks < 4; ++ks) {
        const int cq = 2 * ks + kh;
        v8bf Af = *(const v8bf*)&wc_lds[cq][oh * 32 + col][0];
        acc = __builtin_amdgcn_mfma_f32_32x32x16_bf16(Af, Bf[ks], acc, 0, 0, 0);
    }

    const int r2e = (int)(ridx[wn] >> 16);
    const float* xcol = x0 + ((size_t)(b * Cn + oh * 32) * Hn + h) * Wn + wn;
    float* ocol = out + ((size_t)(b * Cn + oh * 32) * Hn + h) * Wn + wn;

#pragma unroll
    for (int r = 0; r < 16; ++r) {
        int row = (r & 3) + 8 * (r >> 2) + 4 * kh;     // 0..31 within tile
        int o = oh * 32 + row;
        float xv = xcol[(size_t)row * (Hn * Wn)];      // L2 hit
        float res = acc[r] + bias_lds[o] + xv * att_lds[r2e * 68 + o];
        ocol[(size_t)row * (Hn * Wn)] = res;           // 128B coalesced
    }
}

// ---------------------------------------------------------------------------
extern "C" void kernel_launch(void* const* d_in, const int* in_sizes, int n_in,
                              void* d_out, int out_size, void* d_ws, size_t ws_size,
                              hipStream_t stream)
{
    const float* x0     = (const float*)d_in[0];
    const float* deg    = (const float*)d_in[1];
    const float* q_map  = (const float*)d_in[2];
    const float* w_k1   = (const float*)d_in[3];
    const float* w_k2   = (const float*)d_in[4];
    const float* w_conv = (const float*)d_in[5];
    const float* b_conv = (const float*)d_in[6];
    const float* w_ca1  = (const float*)d_in[7];
    const float* w_ca2  = (const float*)d_in[8];
    const float* w_g1   = (const float*)d_in[9];
    const float* b_g1   = (const float*)d_in[10];
    const float* w_g2   = (const float*)d_in[11];
    const float* b_g2   = (const float*)d_in[12];
    float* outp   = (float*)d_out;
    float* kern_g = (float*)d_ws;                           // 8*2304 floats
    float* att_g  = kern_g + Bn * Cn * Rn * 9;              // 8*256 floats
    unsigned short* wbf = (unsigned short*)(att_g + Bn * 256);  // 4096 bf16

    precomp_kernel<<<Bn + 1, 256, 0, stream>>>(deg, w_k1, w_k2, w_ca1, w_ca2,
                                               w_conv, kern_g, att_g, wbf);
    da_main<<<Bn * Hn, 512, 0, stream>>>(x0, q_map, wbf, b_conv,
                                         w_g1, b_g1, w_g2, b_g2,
                                         kern_g, att_g, outp);
}

// Round 14
// 36.621 us; speedup vs baseline: 1.2564x; 1.2564x over previous
//
#include <hip/hip_runtime.h>
#include <hip/hip_bf16.h>
#include <math.h>

// Problem constants
#define Bn 8
#define Cn 64
#define Hn 128
#define Wn 128
#define Rn 4

typedef __bf16 v8bf __attribute__((ext_vector_type(8)));
typedef float  v16f __attribute__((ext_vector_type(16)));

__device__ __forceinline__ float leaky(float x) { return x >= 0.f ? x : 0.1f * x; }

__device__ __forceinline__ unsigned bf16pair(float a, float b) {
    __hip_bfloat16 ha = __float2bfloat16(a);
    __hip_bfloat16 hb = __float2bfloat16(b);
    return (unsigned)*reinterpret_cast<unsigned short*>(&ha) |
           ((unsigned)*reinterpret_cast<unsigned short*>(&hb) << 16);
}

// ---------------------------------------------------------------------------
// Kernel A: per-batch dynamic depthwise kernels + channel attn; block Bn
// converts w_conv -> bf16 [o][c].
//   kern_g[b][c][r][col][row(+pad)]  : b*3072 + c*48 + r*12 + col*4 + row
//   (column-major taps, 16B-aligned per column, for the scatter-form conv)
//   att_g [b][r][c]
// ---------------------------------------------------------------------------
__global__ __launch_bounds__(256) void precomp_kernel(
    const float* __restrict__ deg, const float* __restrict__ w_k1,
    const float* __restrict__ w_k2, const float* __restrict__ w_ca1,
    const float* __restrict__ w_ca2, const float* __restrict__ w_conv,
    float* __restrict__ kern_g, float* __restrict__ att_g,
    unsigned short* __restrict__ wbf)
{
    const int tid = threadIdx.x;
    if (blockIdx.x == Bn) {                       // w_conv -> bf16
        for (int f = tid; f < Cn * Cn; f += 256) {
            __hip_bfloat16 hx = __float2bfloat16(w_conv[f]);
            wbf[f] = *reinterpret_cast<unsigned short*>(&hx);
        }
        return;
    }
    const int b = blockIdx.x;
    __shared__ float y_s[64], a_s[64];
    if (tid < 64) {
        float sy = 0.f, sa = 0.f;
#pragma unroll 8
        for (int j = 0; j < 64; ++j) {
            float d = deg[b * 64 + j];
            sy += d * w_k1[tid * 64 + j];
            sa += d * w_ca1[tid * 64 + j];
        }
        y_s[tid] = leaky(sy);
        a_s[tid] = leaky(sa);
    }
    __syncthreads();
    for (int f = tid; f < Cn * Rn * 9; f += 256) {
        int c = f / 36;
        int j = f - c * 36;
        int r = j / 9;
        int kk = j - r * 9;
        int o = c * 9 + kk;
        const float* wp = &w_k2[(r * 576 + o) * 16];
        const float* yp = &y_s[r * 16];
        float s = 0.f;
#pragma unroll
        for (int i = 0; i < 16; ++i) s += yp[i] * wp[i];
        int row = kk / 3, col = kk - row * 3;     // kk = row*3 + col
        kern_g[b * 3072 + c * 48 + r * 12 + col * 4 + row] = s;
    }
    {
        int r = tid >> 6, o = tid & 63;
        const float* wp = &w_ca2[(r * 64 + o) * 16];
        const float* ap = &a_s[r * 16];
        float s = 0.f;
#pragma unroll
        for (int i = 0; i < 16; ++i) s += ap[i] * wp[i];
        att_g[b * 256 + tid] = 1.f / (1.f + expf(-s));
    }
}

// ---------------------------------------------------------------------------
// Main kernel: one block per (b,h) row, 512 threads = 8 waves, 2 barriers.
// R12 base + SCATTER-FORM depthwise: lane computes from its OWN column taps
// the contributions L (to out w+1, kernel r1(w+1) col0), M (own, col1),
// R (to out w-1, kernel r1(w-1) col2); out = shfl_up(L) + M + shfl_down(R)
// -> 2 shuffles/channel instead of 6. Kern read as 3 b128 column vectors
// (+1 masked edge column). 1-deep pipelined center+edge tap loads (R12).
// ---------------------------------------------------------------------------
__global__ __launch_bounds__(512) void da_main(
    const float* __restrict__ x0, const float* __restrict__ q_map,
    const unsigned short* __restrict__ wbf, const float* __restrict__ b_conv,
    const float* __restrict__ w_g1, const float* __restrict__ b_g1,
    const float* __restrict__ w_g2, const float* __restrict__ b_g2,
    const float* __restrict__ kern_g, const float* __restrict__ att_g,
    float* __restrict__ out)
{
    __shared__ __align__(16) float kern_lds[Cn * 48];           // 12 KB (col-major)
    __shared__ __align__(16) unsigned short wc_lds[8][Cn][8];   // 8 KB
    __shared__ __align__(16) unsigned short t_lds[Wn * Cn];     // 16 KB (XOR-swizzled [w][c])
    __shared__ float att_lds[Rn * 68];                          // 1.1 KB
    __shared__ float bias_lds[Cn];                              // 0.25 KB
    __shared__ unsigned ridx[Wn];                               // 0.5 KB  r1 | r2<<16

    const int tid = threadIdx.x;
    const int ob = blockIdx.x;
    // XCD-aware swizzle: XCD i gets batch i (4 MB image == one L2).
    const int sb = ((ob & 7) << 7) | (ob >> 3);
    const int b = sb >> 7;
    const int h = sb & 127;

    const int lane = tid & 63;
    const int w = tid & 127;
    const int q = tid >> 7;               // channel quarter: [16q, 16q+16)

    // ---- phase 0: staging ----
    for (int f = tid; f < Cn * 48; f += 512)
        kern_lds[f] = kern_g[b * 3072 + f];
    {   // wc subtiles: one conflict-free b128 write per thread
        int cq = tid & 7, o = tid >> 3;
        *(v8bf*)&wc_lds[cq][o][0] = *(const v8bf*)&wbf[o * 64 + cq * 8];
    }
    if (tid < 256) att_lds[(tid >> 6) * 68 + (tid & 63)] = att_g[b * 256 + tid];
    if (tid < 64) bias_lds[tid] = b_conv[tid];

    // routing: once per column, published packed (r1 | r2<<16)
    if (tid < 128) {
        const int wc = tid;
        float qv[9];
#pragma unroll
        for (int dh = 0; dh < 3; ++dh) {
            int row = h - 1 + dh;
#pragma unroll
            for (int dw = 0; dw < 3; ++dw) {
                int col = wc - 1 + dw;
                qv[dh * 3 + dw] = (row >= 0 && row < Hn && col >= 0 && col < Wn)
                                      ? q_map[(b * Hn + row) * Wn + col] : 0.f;
            }
        }
        float best1 = -1e30f, best2 = -1e30f;
        int r1 = 0, r2 = 0;
#pragma unroll
        for (int r = 0; r < Rn; ++r) {
            float s1 = b_g1[r], s2 = b_g2[r];
#pragma unroll
            for (int k = 0; k < 9; ++k) {
                s1 += qv[k] * w_g1[r * 9 + k];
                s2 += qv[k] * w_g2[r * 9 + k];
            }
            if (s1 > best1) { best1 = s1; r1 = r; }   // strict > == first argmax
            if (s2 > best2) { best2 = s2; r2 = r; }
        }
        ridx[wc] = (unsigned)r1 | ((unsigned)r2 << 16);
    }
    __syncthreads();

    // ---- phase 1: scatter-form depthwise, 16 channels/thread, pipelined ----
    const bool okm = (h > 0);
    const bool okp = (h < Hn - 1);
    const float* xbase = x0 + (size_t)(b * Cn) * Hn * Wn + h * Wn + w;
    const int swz = (w & 7) << 4;
    const int r1  = (int)(ridx[w] & 0xffffu);
    const int r1L = (int)(ridx[(w == 0) ? 0 : (w - 1)] & 0xffffu);
    const int r1R = (int)(ridx[(w == 127) ? 127 : (w + 1)] & 0xffffu);
    // kern column byte offsets (within kern_lds[c*48 + ...])
    const int offM = r1 * 12 + 4;          // own kernel, middle column
    const int offL = r1R * 12 + 0;         // right neighbor's kernel, left col
    const int offR = r1L * 12 + 8;         // left neighbor's kernel, right col
    // edge column of OWN kernel: lane0 -> col0 (left-in), lane63 -> col2
    const int offE = r1 * 12 + ((lane == 0) ? 0 : 8);
    // edge tap pointer: lane0 reads w-1, lane63 reads w+1, others own (L1 hit)
    const int eoff = (lane == 0) ? ((w == 0) ? 0 : -1)
                   : (lane == 63) ? ((w == 127) ? 0 : 1) : 0;
    const bool eok = !((lane == 0 && w == 0) || (lane == 63 && w == 127));

    // prefetch registers (pair ahead): center taps + edge taps, 2 channels
    float nvm[2], nv0[2], nvp[2], nem[2], ne0[2], nep[2];

#define LOADP(P)                                                          \
    do {                                                                  \
        _Pragma("unroll")                                                 \
        for (int u = 0; u < 2; ++u) {                                     \
            const float* xc = xbase + (16 * q + 2 * (P) + u) * (Hn * Wn); \
            nvm[u] = okm ? xc[-Wn] : 0.f;                                 \
            nv0[u] = xc[0];                                               \
            nvp[u] = okp ? xc[Wn] : 0.f;                                  \
            const float* xe = xc + eoff;                                  \
            nem[u] = okm ? xe[-Wn] : 0.f;                                 \
            ne0[u] = xe[0];                                               \
            nep[u] = okp ? xe[Wn] : 0.f;                                  \
        }                                                                 \
    } while (0)

    LOADP(0);
#pragma unroll
    for (int p = 0; p < 8; ++p) {
        float avm[2] = {nvm[0], nvm[1]}, av0[2] = {nv0[0], nv0[1]},
              avp[2] = {nvp[0], nvp[1]};
        float aem[2] = {nem[0], nem[1]}, ae0[2] = {ne0[0], ne0[1]},
              aep[2] = {nep[0], nep[1]};
        if (p < 7) LOADP(p + 1);                   // issue next pair's loads

        float tt[2];
#pragma unroll
        for (int u = 0; u < 2; ++u) {
            const int c = 16 * q + 2 * p + u;
            const float* kc = &kern_lds[c * 48];
            float4 kM = *(const float4*)(kc + offM);   // own, middle col
            float4 kL = *(const float4*)(kc + offL);   // for L product
            float4 kR = *(const float4*)(kc + offR);   // for R product
            float4 kE = *(const float4*)(kc + offE);   // edge col (own kernel)
            float vm = avm[u], v0 = av0[u], vp = avp[u];
            float L = vm * kL.x + v0 * kL.y + vp * kL.z;   // -> out(w+1)
            float M = vm * kM.x + v0 * kM.y + vp * kM.z;   // -> out(w)
            float R = vm * kR.x + v0 * kR.y + vp * kR.z;   // -> out(w-1)
            float E = aem[u] * kE.x + ae0[u] * kE.y + aep[u] * kE.z;
            E = eok ? E : 0.f;
            float lin = __shfl_up(L, 1);
            float rin = __shfl_down(R, 1);
            if (lane == 0)  lin = E;
            if (lane == 63) rin = E;
            tt[u] = leaky(lin + M + rin);
        }
        unsigned pk = bf16pair(tt[0], tt[1]);
        int cbyte = (16 * q + 2 * p) * 2;
        *(unsigned*)((char*)t_lds + w * 128 + (cbyte ^ swz)) = pk;
    }
#undef LOADP
    __syncthreads();

    // ---- phase 2: MFMA channel mix + fused epilogue (R10/R12 verified) ----
    const int v = tid >> 6;               // wave 0..7
    const int wt = v & 3;                 // w-tile (32 cols)
    const int oh = v >> 2;                // o-half (32 rows)
    const int col = lane & 31;
    const int kh = lane >> 5;
    const int wn = wt * 32 + col;         // this lane's output column

    v8bf Bf[4];
#pragma unroll
    for (int ks = 0; ks < 4; ++ks) {
        int cbyte = (16 * ks + 8 * kh) * 2;
        Bf[ks] = *(const v8bf*)((const char*)t_lds + wn * 128 + (cbyte ^ ((wn & 7) << 4)));
    }

    v16f acc;
#pragma unroll
    for (int i = 0; i < 16; ++i) acc[i] = 0.f;

#pragma unroll
    for (int ks = 0; ks < 4; ++ks) {
        const int cq = 2 * ks + kh;
        v8bf Af = *(const v8bf*)&wc_lds[cq][oh * 32 + col][0];
        acc = __builtin_amdgcn_mfma_f32_32x32x16_bf16(Af, Bf[ks], acc, 0, 0, 0);
    }

    const int r2e = (int)(ridx[wn] >> 16);
    const float* xcol = x0 + ((size_t)(b * Cn + oh * 32) * Hn + h) * Wn + wn;
    float* ocol = out + ((size_t)(b * Cn + oh * 32) * Hn + h) * Wn + wn;

#pragma unroll
    for (int r = 0; r < 16; ++r) {
        int row = (r & 3) + 8 * (r >> 2) + 4 * kh;     // 0..31 within tile
        int o = oh * 32 + row;
        float xv = xcol[(size_t)row * (Hn * Wn)];      // L2 hit
        float res = acc[r] + bias_lds[o] + xv * att_lds[r2e * 68 + o];
        ocol[(size_t)row * (Hn * Wn)] = res;           // 128B coalesced
    }
}

// ---------------------------------------------------------------------------
extern "C" void kernel_launch(void* const* d_in, const int* in_sizes, int n_in,
                              void* d_out, int out_size, void* d_ws, size_t ws_size,
                              hipStream_t stream)
{
    const float* x0     = (const float*)d_in[0];
    const float* deg    = (const float*)d_in[1];
    const float* q_map  = (const float*)d_in[2];
    const float* w_k1   = (const float*)d_in[3];
    const float* w_k2   = (const float*)d_in[4];
    const float* w_conv = (const float*)d_in[5];
    const float* b_conv = (const float*)d_in[6];
    const float* w_ca1  = (const float*)d_in[7];
    const float* w_ca2  = (const float*)d_in[8];
    const float* w_g1   = (const float*)d_in[9];
    const float* b_g1   = (const float*)d_in[10];
    const float* w_g2   = (const float*)d_in[11];
    const float* b_g2   = (const float*)d_in[12];
    float* outp   = (float*)d_out;
    float* kern_g = (float*)d_ws;                           // 8*3072 floats
    float* att_g  = kern_g + Bn * 3072;                     // 8*256 floats
    unsigned short* wbf = (unsigned short*)(att_g + Bn * 256);  // 4096 bf16

    precomp_kernel<<<Bn + 1, 256, 0, stream>>>(deg, w_k1, w_k2, w_ca1, w_ca2,
                                               w_conv, kern_g, att_g, wbf);
    da_main<<<Bn * Hn, 512, 0, stream>>>(x0, q_map, wbf, b_conv,
                                         w_g1, b_g1, w_g2, b_g2,
                                         kern_g, att_g, outp);
}